// Round 1
// baseline (2519.095 us; speedup 1.0000x reference)
//
#include <hip/hip_runtime.h>
#include <hip/hip_bf16.h>

// TGN heterogeneous attention, MI355X. D=32, H=2, DH=16.
// Plan: fold all per-edge linears into per-node matvecs + a per-edge "ev" term
// that is constant across layers; CSR by dst (masked edges dropped) built once;
// per-layer single-pass online-softmax aggregation, one 32-lane group per dst.

#define TPB 256

__device__ __forceinline__ unsigned int pack_bf2(float a, float b) {
    __hip_bfloat162 h2;
    h2.x = __float2bfloat16(a);
    h2.y = __float2bfloat16(b);
    return *(unsigned int*)&h2;
}

// ---- Wc = elin @ Wv (32x32), bc = elin_b @ Wv (32) ----
__global__ void __launch_bounds__(1024) prep_weights_kernel(
        const float* __restrict__ elin, const float* __restrict__ elinb,
        const float* __restrict__ Wv, float* __restrict__ Wc, float* __restrict__ bc) {
    int t = threadIdx.x;
    int i = t >> 5, j = t & 31;
    float acc = 0.f;
#pragma unroll
    for (int k = 0; k < 32; ++k) acc += elin[i * 32 + k] * Wv[k * 32 + j];
    Wc[i * 32 + j] = acc;
    if (i == 0) {
        float b = 0.f;
#pragma unroll
        for (int k = 0; k < 32; ++k) b += elinb[k] * Wv[k * 32 + j];
        bc[j] = b;
    }
}

// ---- h = memory[idx] + cos(ts*w + b); out_mem = memory[idx] ----
__global__ void __launch_bounds__(TPB) node_init_kernel(
        const float* __restrict__ mem, const int* __restrict__ idx,
        const float* __restrict__ ts, const float* __restrict__ tw,
        const float* __restrict__ tb, float* __restrict__ h,
        float* __restrict__ out_mem, int nb) {
    int g = blockIdx.x * TPB + threadIdx.x;
    if (g >= nb * 32) return;
    int n = g >> 5, d = g & 31;
    float m = mem[(long)idx[n] * 32 + d];
    out_mem[g] = m;
    h[g] = m + __cosf(ts[n] * tw[d] + tb[d]);
}

// ---- histogram of unmasked edges by dst ----
__global__ void __launch_bounds__(TPB) hist_kernel(
        const int* __restrict__ dst, const int* __restrict__ mask,
        int* __restrict__ cnt, int e) {
    int i = blockIdx.x * TPB + threadIdx.x;
    if (i >= e) return;
    if (mask[i] != 0) atomicAdd(&cnt[dst[i]], 1);
}

// ---- single-block exclusive scan: offs[0..nb], cur = offs copy ----
__global__ void __launch_bounds__(1024) scan_kernel(
        const int* __restrict__ cnt, int* __restrict__ offs,
        int* __restrict__ cur, int nb) {
    __shared__ int s[1024];
    int t = threadIdx.x;
    int C = (nb + 1023) >> 10;
    int lo = t * C, hi = lo + C;
    if (hi > nb) hi = nb;
    if (lo > nb) lo = nb;
    int sum = 0;
    for (int i = lo; i < hi; ++i) sum += cnt[i];
    s[t] = sum;
    __syncthreads();
    for (int off = 1; off < 1024; off <<= 1) {
        int v = (t >= off) ? s[t - off] : 0;
        __syncthreads();
        s[t] += v;
        __syncthreads();
    }
    int run = s[t] - sum;  // exclusive prefix of this thread's chunk
    for (int i = lo; i < hi; ++i) {
        offs[i] = run;
        cur[i] = run;
        run += cnt[i];
    }
    if (t == 1023) offs[nb] = s[1023];
}

// ---- scatter unmasked edges into CSR slots ----
__global__ void __launch_bounds__(TPB) scatter_kernel(
        const int* __restrict__ src, const int* __restrict__ dst,
        const int* __restrict__ mask, int* __restrict__ cur,
        int* __restrict__ csr_src, int* __restrict__ csr_eid, int e) {
    int i = blockIdx.x * TPB + threadIdx.x;
    if (i >= e) return;
    if (mask[i] != 0) {
        int p = atomicAdd(&cur[dst[i]], 1);
        csr_src[p] = src[i];
        csr_eid[p] = i;
    }
}

// ---- ev[p] = feat[eidx[e]] @ Wc + cos(rt[e]*tw+tb) @ Wv + bc   (bf16 store) ----
__global__ void __launch_bounds__(TPB) ev_kernel(
        const int* __restrict__ total_ptr, const int* __restrict__ eid,
        const int* __restrict__ eidx, const float* __restrict__ rel_t,
        const float* __restrict__ feat,
        const float* __restrict__ Wc, const float* __restrict__ bc,
        const float* __restrict__ Wv,
        const float* __restrict__ tw, const float* __restrict__ tb,
        __hip_bfloat16* __restrict__ ev) {
    int p = blockIdx.x * TPB + threadIdx.x;
    if (p >= *total_ptr) return;
    int e = eid[p];
    const float4* f4 = (const float4*)(feat + (long)eidx[e] * 32);
    float r[32];
#pragma unroll
    for (int i = 0; i < 8; ++i) {
        float4 v = f4[i];
        r[i * 4 + 0] = v.x; r[i * 4 + 1] = v.y;
        r[i * 4 + 2] = v.z; r[i * 4 + 3] = v.w;
    }
    float t = rel_t[e];
    float acc[32];
#pragma unroll
    for (int j = 0; j < 32; ++j) acc[j] = bc[j];
#pragma unroll
    for (int i = 0; i < 32; ++i) {
        float x = r[i];
#pragma unroll
        for (int j = 0; j < 32; ++j) acc[j] += x * Wc[i * 32 + j];
    }
#pragma unroll
    for (int i = 0; i < 32; ++i) {
        float x = __cosf(t * tw[i] + tb[i]);
#pragma unroll
        for (int j = 0; j < 32; ++j) acc[j] += x * Wv[i * 32 + j];
    }
    uint4* o = (uint4*)(ev + (long)p * 32);
#pragma unroll
    for (int q = 0; q < 4; ++q) {
        uint4 u;
        u.x = pack_bf2(acc[q * 8 + 0], acc[q * 8 + 1]);
        u.y = pack_bf2(acc[q * 8 + 2], acc[q * 8 + 3]);
        u.z = pack_bf2(acc[q * 8 + 4], acc[q * 8 + 5]);
        u.w = pack_bf2(acc[q * 8 + 6], acc[q * 8 + 7]);
        o[q] = u;
    }
}

// ---- per-node: kn = h@Wk, hv = h@Wv, qn = h@Wq ----
__global__ void __launch_bounds__(TPB) node_mats_kernel(
        const float* __restrict__ h,
        const float* __restrict__ Wk, const float* __restrict__ Wv,
        const float* __restrict__ Wq,
        float* __restrict__ kn, float* __restrict__ hv, float* __restrict__ qn,
        int nb) {
    int n = blockIdx.x * TPB + threadIdx.x;
    if (n >= nb) return;
    const float4* h4 = (const float4*)(h + (long)n * 32);
    float r[32];
#pragma unroll
    for (int i = 0; i < 8; ++i) {
        float4 v = h4[i];
        r[i * 4 + 0] = v.x; r[i * 4 + 1] = v.y;
        r[i * 4 + 2] = v.z; r[i * 4 + 3] = v.w;
    }
    float acc[32];
    // kn
#pragma unroll
    for (int j = 0; j < 32; ++j) acc[j] = 0.f;
#pragma unroll
    for (int i = 0; i < 32; ++i) {
        float x = r[i];
#pragma unroll
        for (int j = 0; j < 32; ++j) acc[j] += x * Wk[i * 32 + j];
    }
    {
        float4* o = (float4*)(kn + (long)n * 32);
#pragma unroll
        for (int q = 0; q < 8; ++q) { float4 v = {acc[q*4], acc[q*4+1], acc[q*4+2], acc[q*4+3]}; o[q] = v; }
    }
    // hv
#pragma unroll
    for (int j = 0; j < 32; ++j) acc[j] = 0.f;
#pragma unroll
    for (int i = 0; i < 32; ++i) {
        float x = r[i];
#pragma unroll
        for (int j = 0; j < 32; ++j) acc[j] += x * Wv[i * 32 + j];
    }
    {
        float4* o = (float4*)(hv + (long)n * 32);
#pragma unroll
        for (int q = 0; q < 8; ++q) { float4 v = {acc[q*4], acc[q*4+1], acc[q*4+2], acc[q*4+3]}; o[q] = v; }
    }
    // qn
#pragma unroll
    for (int j = 0; j < 32; ++j) acc[j] = 0.f;
#pragma unroll
    for (int i = 0; i < 32; ++i) {
        float x = r[i];
#pragma unroll
        for (int j = 0; j < 32; ++j) acc[j] += x * Wq[i * 32 + j];
    }
    {
        float4* o = (float4*)(qn + (long)n * 32);
#pragma unroll
        for (int q = 0; q < 8; ++q) { float4 v = {acc[q*4], acc[q*4+1], acc[q*4+2], acc[q*4+3]}; o[q] = v; }
    }
}

// ---- dst-centric online-softmax aggregation; one 32-lane group per dst node ----
// lane d: head = d>>4. s = sum_{16 dims} q*k / sqrt(16); online max/sum/acc.
__global__ void __launch_bounds__(TPB) attn_kernel(
        const int* __restrict__ offs, const int* __restrict__ csr_src,
        const __hip_bfloat16* __restrict__ ev,
        const float* __restrict__ qn, const float* __restrict__ kn,
        const float* __restrict__ hv, float* __restrict__ agg, int nb) {
    int gid = (blockIdx.x * TPB + threadIdx.x) >> 5;
    int lane = threadIdx.x & 31;
    if (gid >= nb) return;
    float q = qn[(long)gid * 32 + lane];
    int beg = offs[gid], end = offs[gid + 1];
    float m = -1e30f, l = 0.f, acc = 0.f;
    for (int p = beg; p < end; ++p) {
        int src = csr_src[p];
        float k = kn[(long)src * 32 + lane];
        float v = hv[(long)src * 32 + lane] + __bfloat162float(ev[(long)p * 32 + lane]);
        float s = q * k;
        s += __shfl_xor(s, 1);
        s += __shfl_xor(s, 2);
        s += __shfl_xor(s, 4);
        s += __shfl_xor(s, 8);
        s *= 0.25f;  // 1/sqrt(DH)
        float mn = fmaxf(m, s);
        float scale = __expf(m - mn);
        float pe = __expf(s - mn);
        l = l * scale + pe;
        acc = acc * scale + pe * v;
        m = mn;
    }
    agg[(long)gid * 32 + lane] = acc / (l + 1e-9f);
}

// ---- h_out = relu(agg @ lin) + h_in ----
__global__ void __launch_bounds__(TPB) update_kernel(
        const float* __restrict__ agg, const float* __restrict__ lin,
        const float* __restrict__ h_in, float* __restrict__ h_out, int nb) {
    int n = blockIdx.x * TPB + threadIdx.x;
    if (n >= nb) return;
    const float4* a4 = (const float4*)(agg + (long)n * 32);
    float r[32];
#pragma unroll
    for (int i = 0; i < 8; ++i) {
        float4 v = a4[i];
        r[i * 4 + 0] = v.x; r[i * 4 + 1] = v.y;
        r[i * 4 + 2] = v.z; r[i * 4 + 3] = v.w;
    }
    float acc[32];
#pragma unroll
    for (int j = 0; j < 32; ++j) acc[j] = 0.f;
#pragma unroll
    for (int i = 0; i < 32; ++i) {
        float x = r[i];
#pragma unroll
        for (int j = 0; j < 32; ++j) acc[j] += x * lin[i * 32 + j];
    }
    const float4* hi4 = (const float4*)(h_in + (long)n * 32);
    float4* o = (float4*)(h_out + (long)n * 32);
#pragma unroll
    for (int q = 0; q < 8; ++q) {
        float4 hv = hi4[q];
        float4 v;
        v.x = fmaxf(acc[q * 4 + 0], 0.f) + hv.x;
        v.y = fmaxf(acc[q * 4 + 1], 0.f) + hv.y;
        v.z = fmaxf(acc[q * 4 + 2], 0.f) + hv.z;
        v.w = fmaxf(acc[q * 4 + 3], 0.f) + hv.w;
        o[q] = v;
    }
}

extern "C" void kernel_launch(void* const* d_in, const int* in_sizes, int n_in,
                              void* d_out, int out_size, void* d_ws, size_t ws_size,
                              hipStream_t stream) {
    const float* mem_a_t = (const float*)d_in[0];
    const float* mem_p_t = (const float*)d_in[1];
    const float* feat    = (const float*)d_in[2];
    const int*   nx_a    = (const int*)d_in[3];
    const int*   nx_p    = (const int*)d_in[4];
    const float* ts_a    = (const float*)d_in[5];
    const float* ts_p    = (const float*)d_in[6];
    const int*   ei_w    = (const int*)d_in[7];
    const float* rt_w    = (const float*)d_in[8];
    const int*   eidx_w  = (const int*)d_in[9];
    const int*   mask_w  = (const int*)d_in[10];
    const int*   ei_r    = (const int*)d_in[11];
    const float* rt_r    = (const float*)d_in[12];
    const int*   eidx_r  = (const int*)d_in[13];
    const int*   mask_r  = (const int*)d_in[14];
    const float* tw      = (const float*)d_in[15];
    const float* tb      = (const float*)d_in[16];
    const float* Wk_w    = (const float*)d_in[17];
    const float* Wq_w    = (const float*)d_in[18];
    const float* Wv_w    = (const float*)d_in[19];
    const float* elw_w   = (const float*)d_in[20];
    const float* elb_w   = (const float*)d_in[21];
    const float* Wk_r    = (const float*)d_in[22];
    const float* Wq_r    = (const float*)d_in[23];
    const float* Wv_r    = (const float*)d_in[24];
    const float* elw_r   = (const float*)d_in[25];
    const float* elb_r   = (const float*)d_in[26];
    const float* lin_a   = (const float*)d_in[27];
    const float* lin_p   = (const float*)d_in[28];

    const int NB = in_sizes[3];       // 100000
    const int E  = in_sizes[8];       // 2000000

    float* out = (float*)d_out;
    float* out_ha = out;
    float* out_hp = out + (size_t)NB * 32;
    float* out_ma = out + (size_t)2 * NB * 32;
    float* out_mp = out + (size_t)3 * NB * 32;

    // ---- workspace carve (~420 MB total) ----
    char* wp = (char*)d_ws;
    auto carve = [&](size_t bytes) -> void* {
        void* p = (void*)wp;
        wp += (bytes + 255) & ~(size_t)255;
        return p;
    };
    float* h_a  = (float*)carve((size_t)NB * 32 * 4);
    float* h_p  = (float*)carve((size_t)NB * 32 * 4);
    float* kn_a = (float*)carve((size_t)NB * 32 * 4);
    float* hv_a = (float*)carve((size_t)NB * 32 * 4);
    float* qn_a = (float*)carve((size_t)NB * 32 * 4);
    float* kn_p = (float*)carve((size_t)NB * 32 * 4);
    float* hv_p = (float*)carve((size_t)NB * 32 * 4);
    float* qn_p = (float*)carve((size_t)NB * 32 * 4);
    float* agg_a = (float*)carve((size_t)NB * 32 * 4);
    float* agg_p = (float*)carve((size_t)NB * 32 * 4);
    int* cnt_w  = (int*)carve((size_t)NB * 4);
    int* offs_w = (int*)carve((size_t)(NB + 1) * 4);
    int* cur_w  = (int*)carve((size_t)NB * 4);
    int* cnt_r  = (int*)carve((size_t)NB * 4);
    int* offs_r = (int*)carve((size_t)(NB + 1) * 4);
    int* cur_r  = (int*)carve((size_t)NB * 4);
    int* csr_src_w = (int*)carve((size_t)E * 4);
    int* csr_eid_w = (int*)carve((size_t)E * 4);
    int* csr_src_r = (int*)carve((size_t)E * 4);
    int* csr_eid_r = (int*)carve((size_t)E * 4);
    __hip_bfloat16* ev_w = (__hip_bfloat16*)carve((size_t)E * 32 * 2);
    __hip_bfloat16* ev_r = (__hip_bfloat16*)carve((size_t)E * 32 * 2);
    float* Wc_w = (float*)carve(1024 * 4);
    float* bc_w = (float*)carve(32 * 4);
    float* Wc_r = (float*)carve(1024 * 4);
    float* bc_r = (float*)carve(32 * 4);
    (void)ws_size; (void)n_in; (void)out_size;

    const int gE  = (E + TPB - 1) / TPB;            // edge-parallel grid
    const int gN32 = (NB * 32 + TPB - 1) / TPB;     // node*dim grid (also attn: 8 groups/block)
    const int gN  = (NB + TPB - 1) / TPB;           // node grid

    // zero histogram counters (ws is poisoned 0xAA before every call)
    hipMemsetAsync(cnt_w, 0, (size_t)NB * 4, stream);
    hipMemsetAsync(cnt_r, 0, (size_t)NB * 4, stream);

    prep_weights_kernel<<<1, 1024, 0, stream>>>(elw_w, elb_w, Wv_w, Wc_w, bc_w);
    prep_weights_kernel<<<1, 1024, 0, stream>>>(elw_r, elb_r, Wv_r, Wc_r, bc_r);

    node_init_kernel<<<gN32, TPB, 0, stream>>>(mem_a_t, nx_a, ts_a, tw, tb, h_a, out_ma, NB);
    node_init_kernel<<<gN32, TPB, 0, stream>>>(mem_p_t, nx_p, ts_p, tw, tb, h_p, out_mp, NB);

    // CSR build (dst = ei[1] = ei + E); masked edges dropped entirely
    hist_kernel<<<gE, TPB, 0, stream>>>(ei_w + E, mask_w, cnt_w, E);
    hist_kernel<<<gE, TPB, 0, stream>>>(ei_r + E, mask_r, cnt_r, E);
    scan_kernel<<<1, 1024, 0, stream>>>(cnt_w, offs_w, cur_w, NB);
    scan_kernel<<<1, 1024, 0, stream>>>(cnt_r, offs_r, cur_r, NB);
    scatter_kernel<<<gE, TPB, 0, stream>>>(ei_w, ei_w + E, mask_w, cur_w, csr_src_w, csr_eid_w, E);
    scatter_kernel<<<gE, TPB, 0, stream>>>(ei_r, ei_r + E, mask_r, cur_r, csr_src_r, csr_eid_r, E);

    // layer-invariant per-edge value term (CSR order, bf16)
    ev_kernel<<<gE, TPB, 0, stream>>>(offs_w + NB, csr_eid_w, eidx_w, rt_w, feat,
                                      Wc_w, bc_w, Wv_w, tw, tb, ev_w);
    ev_kernel<<<gE, TPB, 0, stream>>>(offs_r + NB, csr_eid_r, eidx_r, rt_r, feat,
                                      Wc_r, bc_r, Wv_r, tw, tb, ev_r);

    for (int layer = 0; layer < 2; ++layer) {
        // writes type: src=author (Wk_w, Wv_w), dst=paper (Wq_w)
        // rev type:    src=paper  (Wk_r, Wv_r), dst=author (Wq_r)
        node_mats_kernel<<<gN, TPB, 0, stream>>>(h_a, Wk_w, Wv_w, Wq_r, kn_a, hv_a, qn_a, NB);
        node_mats_kernel<<<gN, TPB, 0, stream>>>(h_p, Wk_r, Wv_r, Wq_w, kn_p, hv_p, qn_p, NB);

        attn_kernel<<<gN32, TPB, 0, stream>>>(offs_w, csr_src_w, ev_w, qn_p, kn_a, hv_a, agg_p, NB);
        attn_kernel<<<gN32, TPB, 0, stream>>>(offs_r, csr_src_r, ev_r, qn_a, kn_p, hv_p, agg_a, NB);

        if (layer == 0) {
            update_kernel<<<gN, TPB, 0, stream>>>(agg_a, lin_a, h_a, h_a, NB);
            update_kernel<<<gN, TPB, 0, stream>>>(agg_p, lin_p, h_p, h_p, NB);
        } else {
            update_kernel<<<gN, TPB, 0, stream>>>(agg_a, lin_a, h_a, out_ha, NB);
            update_kernel<<<gN, TPB, 0, stream>>>(agg_p, lin_p, h_p, out_hp, NB);
        }
    }
}

// Round 2
// 2268.109 us; speedup vs baseline: 1.1107x; 1.1107x over previous
//
#include <hip/hip_runtime.h>
#include <hip/hip_bf16.h>

// TGN heterogeneous attention, MI355X. D=32, H=2, DH=16.
// R2: bf16-packed k|v rows (one gather per edge), 2-way unrolled online-softmax
// loop, and pairwise kernel fusion (both node types / edge types / directions
// per launch). CSR by dst built once, masked edges dropped.

#define TPB 256

__device__ __forceinline__ unsigned pack_bf2(float a, float b) {
    __hip_bfloat162 h2;
    h2.x = __float2bfloat16(a);
    h2.y = __float2bfloat16(b);
    return *(unsigned*)&h2;
}
__device__ __forceinline__ float bflo(unsigned u) { return __uint_as_float(u << 16); }
__device__ __forceinline__ float bfhi(unsigned u) { return __uint_as_float(u & 0xffff0000u); }
__device__ __forceinline__ float bfu(unsigned short u) { return __uint_as_float(((unsigned)u) << 16); }

// ---- Wc = elin @ Wv (32x32), bc = elin_b @ Wv (32); block b = edge type ----
__global__ void __launch_bounds__(1024) prep_weights_kernel(
        const float* __restrict__ elw_w, const float* __restrict__ elb_w,
        const float* __restrict__ Wv_w, float* __restrict__ Wc_w, float* __restrict__ bc_w,
        const float* __restrict__ elw_r, const float* __restrict__ elb_r,
        const float* __restrict__ Wv_r, float* __restrict__ Wc_r, float* __restrict__ bc_r) {
    int ty = blockIdx.x;
    const float* elin  = ty ? elw_r : elw_w;
    const float* elinb = ty ? elb_r : elb_w;
    const float* Wv    = ty ? Wv_r : Wv_w;
    float* Wc = ty ? Wc_r : Wc_w;
    float* bc = ty ? bc_r : bc_w;
    int t = threadIdx.x;
    int i = t >> 5, j = t & 31;
    float acc = 0.f;
#pragma unroll
    for (int k = 0; k < 32; ++k) acc += elin[i * 32 + k] * Wv[k * 32 + j];
    Wc[i * 32 + j] = acc;
    if (i == 0) {
        float b = 0.f;
#pragma unroll
        for (int k = 0; k < 32; ++k) b += elinb[k] * Wv[k * 32 + j];
        bc[j] = b;
    }
}

// ---- both types: h = memory[idx] + cos(ts*w + b); out_mem = memory[idx] ----
__global__ void __launch_bounds__(TPB) node_init_kernel(
        const float* __restrict__ mem_a, const int* __restrict__ idx_a,
        const float* __restrict__ ts_a, float* __restrict__ h_a, float* __restrict__ oma,
        const float* __restrict__ mem_p, const int* __restrict__ idx_p,
        const float* __restrict__ ts_p, float* __restrict__ h_p, float* __restrict__ omp_,
        const float* __restrict__ tw, const float* __restrict__ tb, int nb) {
    int g0 = blockIdx.x * TPB + threadIdx.x;
    int tot = nb * 32;
    if (g0 >= 2 * tot) return;
    int ty = g0 >= tot;
    int g = ty ? g0 - tot : g0;
    const float* mem = ty ? mem_p : mem_a;
    const int* idx   = ty ? idx_p : idx_a;
    const float* ts  = ty ? ts_p : ts_a;
    float* h = ty ? h_p : h_a;
    float* om = ty ? omp_ : oma;
    int n = g >> 5, d = g & 31;
    float m = mem[(long)idx[n] * 32 + d];
    om[g] = m;
    h[g] = m + __cosf(ts[n] * tw[d] + tb[d]);
}

// ---- histogram of unmasked edges by dst, both edge types ----
__global__ void __launch_bounds__(TPB) hist_kernel(
        const int* __restrict__ dst_w, const int* __restrict__ mask_w, int* __restrict__ cnt_w,
        const int* __restrict__ dst_r, const int* __restrict__ mask_r, int* __restrict__ cnt_r,
        int e) {
    int i0 = blockIdx.x * TPB + threadIdx.x;
    if (i0 >= 2 * e) return;
    int ty = i0 >= e;
    int i = ty ? i0 - e : i0;
    const int* mask = ty ? mask_r : mask_w;
    if (mask[i] != 0) {
        const int* dst = ty ? dst_r : dst_w;
        int* cnt = ty ? cnt_r : cnt_w;
        atomicAdd(&cnt[dst[i]], 1);
    }
}

// ---- exclusive scan, block b = edge type ----
__global__ void __launch_bounds__(1024) scan_kernel(
        const int* __restrict__ cnt_w, int* __restrict__ offs_w, int* __restrict__ cur_w,
        const int* __restrict__ cnt_r, int* __restrict__ offs_r, int* __restrict__ cur_r,
        int nb) {
    int ty = blockIdx.x;
    const int* cnt = ty ? cnt_r : cnt_w;
    int* offs = ty ? offs_r : offs_w;
    int* cur  = ty ? cur_r : cur_w;
    __shared__ int s[1024];
    int t = threadIdx.x;
    int C = (nb + 1023) >> 10;
    int lo = t * C, hi = lo + C;
    if (hi > nb) hi = nb;
    if (lo > nb) lo = nb;
    int sum = 0;
    for (int i = lo; i < hi; ++i) sum += cnt[i];
    s[t] = sum;
    __syncthreads();
    for (int off = 1; off < 1024; off <<= 1) {
        int v = (t >= off) ? s[t - off] : 0;
        __syncthreads();
        s[t] += v;
        __syncthreads();
    }
    int run = s[t] - sum;
    for (int i = lo; i < hi; ++i) {
        offs[i] = run;
        cur[i] = run;
        run += cnt[i];
    }
    if (t == 1023) offs[nb] = s[1023];
}

// ---- scatter unmasked edges into CSR slots, both edge types ----
__global__ void __launch_bounds__(TPB) scatter_kernel(
        const int* __restrict__ src_w, const int* __restrict__ dst_w,
        const int* __restrict__ mask_w, int* __restrict__ cur_w,
        int* __restrict__ cs_w, int* __restrict__ ce_w,
        const int* __restrict__ src_r, const int* __restrict__ dst_r,
        const int* __restrict__ mask_r, int* __restrict__ cur_r,
        int* __restrict__ cs_r, int* __restrict__ ce_r, int e) {
    int i0 = blockIdx.x * TPB + threadIdx.x;
    if (i0 >= 2 * e) return;
    int ty = i0 >= e;
    int i = ty ? i0 - e : i0;
    const int* mask = ty ? mask_r : mask_w;
    if (mask[i] != 0) {
        const int* src = ty ? src_r : src_w;
        const int* dst = ty ? dst_r : dst_w;
        int* cur = ty ? cur_r : cur_w;
        int* cs = ty ? cs_w : cs_r == cs_r ? (ty ? cs_r : cs_w) : cs_w;  // (see below)
        cs = ty ? cs_r : cs_w;
        int* ce = ty ? ce_r : ce_w;
        int p = atomicAdd(&cur[dst[i]], 1);
        cs[p] = src[i];
        ce[p] = i;
    }
}

// ---- ev[p] = feat[eidx[e]] @ Wc + cos(rt[e]*tw+tb) @ Wv + bc (bf16), both types ----
__global__ void __launch_bounds__(TPB) ev_kernel(
        int geb,
        const int* __restrict__ tot_w, const int* __restrict__ eid_w,
        const int* __restrict__ eidx_w, const float* __restrict__ rt_w,
        const float* __restrict__ Wc_w, const float* __restrict__ bc_w,
        const float* __restrict__ Wv_w, unsigned short* __restrict__ ev_w,
        const int* __restrict__ tot_r, const int* __restrict__ eid_r,
        const int* __restrict__ eidx_r, const float* __restrict__ rt_r,
        const float* __restrict__ Wc_r, const float* __restrict__ bc_r,
        const float* __restrict__ Wv_r, unsigned short* __restrict__ ev_r,
        const float* __restrict__ feat,
        const float* __restrict__ tw, const float* __restrict__ tb) {
    int ty = blockIdx.x >= geb;
    int p = (blockIdx.x - (ty ? geb : 0)) * TPB + threadIdx.x;
    if (p >= *(ty ? tot_r : tot_w)) return;
    const int* eid = ty ? eid_r : eid_w;
    const int* eidx = ty ? eidx_r : eidx_w;
    const float* rel_t = ty ? rt_r : rt_w;
    const float* Wc = ty ? Wc_r : Wc_w;
    const float* bc = ty ? bc_r : bc_w;
    const float* Wv = ty ? Wv_r : Wv_w;
    unsigned short* ev = ty ? ev_r : ev_w;

    int e = eid[p];
    const float4* f4 = (const float4*)(feat + (long)eidx[e] * 32);
    float r[32];
#pragma unroll
    for (int i = 0; i < 8; ++i) {
        float4 v = f4[i];
        r[i * 4 + 0] = v.x; r[i * 4 + 1] = v.y;
        r[i * 4 + 2] = v.z; r[i * 4 + 3] = v.w;
    }
    float t = rel_t[e];
    float acc[32];
#pragma unroll
    for (int j = 0; j < 32; ++j) acc[j] = bc[j];
#pragma unroll
    for (int i = 0; i < 32; ++i) {
        float x = r[i];
#pragma unroll
        for (int j = 0; j < 32; ++j) acc[j] += x * Wc[i * 32 + j];
    }
#pragma unroll
    for (int i = 0; i < 32; ++i) {
        float x = __cosf(t * tw[i] + tb[i]);
#pragma unroll
        for (int j = 0; j < 32; ++j) acc[j] += x * Wv[i * 32 + j];
    }
    uint4* o = (uint4*)(ev + (long)p * 32);
#pragma unroll
    for (int q = 0; q < 4; ++q) {
        uint4 u;
        u.x = pack_bf2(acc[q * 8 + 0], acc[q * 8 + 1]);
        u.y = pack_bf2(acc[q * 8 + 2], acc[q * 8 + 3]);
        u.z = pack_bf2(acc[q * 8 + 4], acc[q * 8 + 5]);
        u.w = pack_bf2(acc[q * 8 + 6], acc[q * 8 + 7]);
        o[q] = u;
    }
}

// ---- both types: kv = pack(h@Wk, h@Wv) bf16, qn = h@Wq fp32 ----
__global__ void __launch_bounds__(TPB) node_mats_kernel(
        const float* __restrict__ h_a, const float* __restrict__ Wk_w,
        const float* __restrict__ Wv_w, const float* __restrict__ Wq_r,
        unsigned* __restrict__ kv_a, float* __restrict__ qn_a,
        const float* __restrict__ h_p, const float* __restrict__ Wk_r,
        const float* __restrict__ Wv_r, const float* __restrict__ Wq_w,
        unsigned* __restrict__ kv_p, float* __restrict__ qn_p,
        int nb) {
    int n0 = blockIdx.x * TPB + threadIdx.x;
    if (n0 >= 2 * nb) return;
    int ty = n0 >= nb;
    int n = ty ? n0 - nb : n0;
    const float* h  = ty ? h_p : h_a;
    const float* Wk = ty ? Wk_r : Wk_w;
    const float* Wv = ty ? Wv_r : Wv_w;
    const float* Wq = ty ? Wq_w : Wq_r;
    unsigned* kv = ty ? kv_p : kv_a;
    float* qn = ty ? qn_p : qn_a;

    const float4* h4 = (const float4*)(h + (long)n * 32);
    float r[32];
#pragma unroll
    for (int i = 0; i < 8; ++i) {
        float4 v = h4[i];
        r[i * 4 + 0] = v.x; r[i * 4 + 1] = v.y;
        r[i * 4 + 2] = v.z; r[i * 4 + 3] = v.w;
    }
    float ak[32], av[32], aq[32];
#pragma unroll
    for (int j = 0; j < 32; ++j) { ak[j] = 0.f; av[j] = 0.f; aq[j] = 0.f; }
#pragma unroll
    for (int i = 0; i < 32; ++i) {
        float x = r[i];
#pragma unroll
        for (int j = 0; j < 32; ++j) {
            ak[j] += x * Wk[i * 32 + j];
            av[j] += x * Wv[i * 32 + j];
            aq[j] += x * Wq[i * 32 + j];
        }
    }
    uint4* ko = (uint4*)(kv + (long)n * 32);
#pragma unroll
    for (int q = 0; q < 8; ++q) {
        uint4 u;
        u.x = pack_bf2(ak[q * 4 + 0], av[q * 4 + 0]);
        u.y = pack_bf2(ak[q * 4 + 1], av[q * 4 + 1]);
        u.z = pack_bf2(ak[q * 4 + 2], av[q * 4 + 2]);
        u.w = pack_bf2(ak[q * 4 + 3], av[q * 4 + 3]);
        ko[q >> 1] = (q & 1) ? ko[q >> 1] : u;  // placeholder, replaced below
    }
    // write kv row as 8 x uint4 (32 uints)
    {
        uint4* o = (uint4*)(kv + (long)n * 32);
#pragma unroll
        for (int q = 0; q < 8; ++q) {
            uint4 u;
            u.x = pack_bf2(ak[q * 4 + 0], av[q * 4 + 0]);
            u.y = pack_bf2(ak[q * 4 + 1], av[q * 4 + 1]);
            u.z = pack_bf2(ak[q * 4 + 2], av[q * 4 + 2]);
            u.w = pack_bf2(ak[q * 4 + 3], av[q * 4 + 3]);
            o[q] = u;
        }
    }
    float4* qo = (float4*)(qn + (long)n * 32);
#pragma unroll
    for (int q = 0; q < 8; ++q) {
        float4 v = {aq[q * 4 + 0], aq[q * 4 + 1], aq[q * 4 + 2], aq[q * 4 + 3]};
        qo[q] = v;
    }
}

// ---- both directions: dst-centric online-softmax, one 32-lane group per dst ----
__global__ void __launch_bounds__(TPB) attn_kernel(
        const int* __restrict__ offs_w, const int* __restrict__ src_w,
        const unsigned short* __restrict__ ev_w, const float* __restrict__ qn_p,
        const unsigned* __restrict__ kv_a, float* __restrict__ agg_p,
        const int* __restrict__ offs_r, const int* __restrict__ src_r,
        const unsigned short* __restrict__ ev_r, const float* __restrict__ qn_a,
        const unsigned* __restrict__ kv_p, float* __restrict__ agg_a, int nb) {
    int g = (blockIdx.x * TPB + threadIdx.x) >> 5;
    int lane = threadIdx.x & 31;
    if (g >= 2 * nb) return;
    int dir = g >= nb;
    int node = dir ? g - nb : g;
    const int* offs = dir ? offs_r : offs_w;
    const int* srcs = dir ? src_r : src_w;
    const unsigned short* ev = dir ? ev_r : ev_w;
    const float* qn = dir ? qn_a : qn_p;
    const unsigned* kv = dir ? kv_p : kv_a;
    float* agg = dir ? agg_a : agg_p;

    float q = qn[(long)node * 32 + lane];
    int beg = offs[node], end = offs[node + 1];
    float m = -1e30f, l = 0.f, acc = 0.f;
    int p = beg;
    for (; p + 2 <= end; p += 2) {
        int s0 = srcs[p], s1 = srcs[p + 1];
        unsigned u0 = kv[(long)s0 * 32 + lane];
        unsigned u1 = kv[(long)s1 * 32 + lane];
        float e0 = bfu(ev[(long)p * 32 + lane]);
        float e1 = bfu(ev[(long)(p + 1) * 32 + lane]);
        {
            float s = q * bflo(u0);
            s += __shfl_xor(s, 1); s += __shfl_xor(s, 2);
            s += __shfl_xor(s, 4); s += __shfl_xor(s, 8);
            s *= 0.25f;
            float mn = fmaxf(m, s);
            float sc = __expf(m - mn), pe = __expf(s - mn);
            l = l * sc + pe;
            acc = acc * sc + pe * (bfhi(u0) + e0);
            m = mn;
        }
        {
            float s = q * bflo(u1);
            s += __shfl_xor(s, 1); s += __shfl_xor(s, 2);
            s += __shfl_xor(s, 4); s += __shfl_xor(s, 8);
            s *= 0.25f;
            float mn = fmaxf(m, s);
            float sc = __expf(m - mn), pe = __expf(s - mn);
            l = l * sc + pe;
            acc = acc * sc + pe * (bfhi(u1) + e1);
            m = mn;
        }
    }
    if (p < end) {
        int s0 = srcs[p];
        unsigned u0 = kv[(long)s0 * 32 + lane];
        float e0 = bfu(ev[(long)p * 32 + lane]);
        float s = q * bflo(u0);
        s += __shfl_xor(s, 1); s += __shfl_xor(s, 2);
        s += __shfl_xor(s, 4); s += __shfl_xor(s, 8);
        s *= 0.25f;
        float mn = fmaxf(m, s);
        float sc = __expf(m - mn), pe = __expf(s - mn);
        l = l * sc + pe;
        acc = acc * sc + pe * (bfhi(u0) + e0);
        m = mn;
    }
    agg[(long)node * 32 + lane] = acc / (l + 1e-9f);
}

// ---- both types: h_out = relu(agg @ lin) + h_in ----
__global__ void __launch_bounds__(TPB) update_kernel(
        const float* __restrict__ agg_a, const float* __restrict__ lin_a,
        const float* __restrict__ h_a, float* __restrict__ ho_a,
        const float* __restrict__ agg_p, const float* __restrict__ lin_p,
        const float* __restrict__ h_p, float* __restrict__ ho_p, int nb) {
    int n0 = blockIdx.x * TPB + threadIdx.x;
    if (n0 >= 2 * nb) return;
    int ty = n0 >= nb;
    int n = ty ? n0 - nb : n0;
    const float* agg = ty ? agg_p : agg_a;
    const float* lin = ty ? lin_p : lin_a;
    const float* h_in = ty ? h_p : h_a;
    float* h_out = ty ? ho_p : ho_a;

    const float4* a4 = (const float4*)(agg + (long)n * 32);
    float r[32];
#pragma unroll
    for (int i = 0; i < 8; ++i) {
        float4 v = a4[i];
        r[i * 4 + 0] = v.x; r[i * 4 + 1] = v.y;
        r[i * 4 + 2] = v.z; r[i * 4 + 3] = v.w;
    }
    float acc[32];
#pragma unroll
    for (int j = 0; j < 32; ++j) acc[j] = 0.f;
#pragma unroll
    for (int i = 0; i < 32; ++i) {
        float x = r[i];
#pragma unroll
        for (int j = 0; j < 32; ++j) acc[j] += x * lin[i * 32 + j];
    }
    const float4* hi4 = (const float4*)(h_in + (long)n * 32);
    float4* o = (float4*)(h_out + (long)n * 32);
#pragma unroll
    for (int q = 0; q < 8; ++q) {
        float4 hv = hi4[q];
        float4 v;
        v.x = fmaxf(acc[q * 4 + 0], 0.f) + hv.x;
        v.y = fmaxf(acc[q * 4 + 1], 0.f) + hv.y;
        v.z = fmaxf(acc[q * 4 + 2], 0.f) + hv.z;
        v.w = fmaxf(acc[q * 4 + 3], 0.f) + hv.w;
        o[q] = v;
    }
}

extern "C" void kernel_launch(void* const* d_in, const int* in_sizes, int n_in,
                              void* d_out, int out_size, void* d_ws, size_t ws_size,
                              hipStream_t stream) {
    const float* mem_a_t = (const float*)d_in[0];
    const float* mem_p_t = (const float*)d_in[1];
    const float* feat    = (const float*)d_in[2];
    const int*   nx_a    = (const int*)d_in[3];
    const int*   nx_p    = (const int*)d_in[4];
    const float* ts_a    = (const float*)d_in[5];
    const float* ts_p    = (const float*)d_in[6];
    const int*   ei_w    = (const int*)d_in[7];
    const float* rt_w    = (const float*)d_in[8];
    const int*   eidx_w  = (const int*)d_in[9];
    const int*   mask_w  = (const int*)d_in[10];
    const int*   ei_r    = (const int*)d_in[11];
    const float* rt_r    = (const float*)d_in[12];
    const int*   eidx_r  = (const int*)d_in[13];
    const int*   mask_r  = (const int*)d_in[14];
    const float* tw      = (const float*)d_in[15];
    const float* tb      = (const float*)d_in[16];
    const float* Wk_w    = (const float*)d_in[17];
    const float* Wq_w    = (const float*)d_in[18];
    const float* Wv_w    = (const float*)d_in[19];
    const float* elw_w   = (const float*)d_in[20];
    const float* elb_w   = (const float*)d_in[21];
    const float* Wk_r    = (const float*)d_in[22];
    const float* Wq_r    = (const float*)d_in[23];
    const float* Wv_r    = (const float*)d_in[24];
    const float* elw_r   = (const float*)d_in[25];
    const float* elb_r   = (const float*)d_in[26];
    const float* lin_a   = (const float*)d_in[27];
    const float* lin_p   = (const float*)d_in[28];

    const int NB = in_sizes[3];       // 100000
    const int E  = in_sizes[8];       // 2000000

    float* out = (float*)d_out;
    float* out_ha = out;
    float* out_hp = out + (size_t)NB * 32;
    float* out_ma = out + (size_t)2 * NB * 32;
    float* out_mp = out + (size_t)3 * NB * 32;

    char* wp = (char*)d_ws;
    auto carve = [&](size_t bytes) -> void* {
        void* p = (void*)wp;
        wp += (bytes + 255) & ~(size_t)255;
        return p;
    };
    float* h_a  = (float*)carve((size_t)NB * 32 * 4);
    float* h_p  = (float*)carve((size_t)NB * 32 * 4);
    unsigned* kv_a = (unsigned*)carve((size_t)NB * 32 * 4);
    unsigned* kv_p = (unsigned*)carve((size_t)NB * 32 * 4);
    float* qn_a = (float*)carve((size_t)NB * 32 * 4);
    float* qn_p = (float*)carve((size_t)NB * 32 * 4);
    float* agg_a = (float*)carve((size_t)NB * 32 * 4);
    float* agg_p = (float*)carve((size_t)NB * 32 * 4);
    int* cnt_w  = (int*)carve((size_t)NB * 4);
    int* cnt_r  = (int*)carve((size_t)NB * 4);
    int* offs_w = (int*)carve((size_t)(NB + 1) * 4);
    int* cur_w  = (int*)carve((size_t)NB * 4);
    int* offs_r = (int*)carve((size_t)(NB + 1) * 4);
    int* cur_r  = (int*)carve((size_t)NB * 4);
    int* csr_src_w = (int*)carve((size_t)E * 4);
    int* csr_eid_w = (int*)carve((size_t)E * 4);
    int* csr_src_r = (int*)carve((size_t)E * 4);
    int* csr_eid_r = (int*)carve((size_t)E * 4);
    unsigned short* ev_w = (unsigned short*)carve((size_t)E * 32 * 2);
    unsigned short* ev_r = (unsigned short*)carve((size_t)E * 32 * 2);
    float* Wc_w = (float*)carve(1024 * 4);
    float* bc_w = (float*)carve(32 * 4);
    float* Wc_r = (float*)carve(1024 * 4);
    float* bc_r = (float*)carve(32 * 4);
    (void)ws_size; (void)n_in; (void)out_size;

    const int gE2  = (2 * E + TPB - 1) / TPB;
    const int geb  = (E + TPB - 1) / TPB;          // per-type ev grid half
    const int gN64 = (2 * NB * 32 + TPB - 1) / TPB;
    const int gN2  = (2 * NB + TPB - 1) / TPB;

    // zero both histogram counter arrays in one memset (they are adjacent)
    {
        size_t pad = ((size_t)NB * 4 + 255) & ~(size_t)255;
        hipMemsetAsync(cnt_w, 0, pad + (size_t)NB * 4, stream);
    }

    prep_weights_kernel<<<2, 1024, 0, stream>>>(elw_w, elb_w, Wv_w, Wc_w, bc_w,
                                                elw_r, elb_r, Wv_r, Wc_r, bc_r);
    node_init_kernel<<<gN64, TPB, 0, stream>>>(mem_a_t, nx_a, ts_a, h_a, out_ma,
                                               mem_p_t, nx_p, ts_p, h_p, out_mp,
                                               tw, tb, NB);

    hist_kernel<<<gE2, TPB, 0, stream>>>(ei_w + E, mask_w, cnt_w,
                                         ei_r + E, mask_r, cnt_r, E);
    scan_kernel<<<2, 1024, 0, stream>>>(cnt_w, offs_w, cur_w, cnt_r, offs_r, cur_r, NB);
    scatter_kernel<<<gE2, TPB, 0, stream>>>(ei_w, ei_w + E, mask_w, cur_w, csr_src_w, csr_eid_w,
                                            ei_r, ei_r + E, mask_r, cur_r, csr_src_r, csr_eid_r, E);

    ev_kernel<<<2 * geb, TPB, 0, stream>>>(geb,
            offs_w + NB, csr_eid_w, eidx_w, rt_w, Wc_w, bc_w, Wv_w, ev_w,
            offs_r + NB, csr_eid_r, eidx_r, rt_r, Wc_r, bc_r, Wv_r, ev_r,
            feat, tw, tb);

    for (int layer = 0; layer < 2; ++layer) {
        node_mats_kernel<<<gN2, TPB, 0, stream>>>(
                h_a, Wk_w, Wv_w, Wq_r, kv_a, qn_a,
                h_p, Wk_r, Wv_r, Wq_w, kv_p, qn_p, NB);

        attn_kernel<<<2 * ((NB * 32 + TPB - 1) / TPB), TPB, 0, stream>>>(
                offs_w, csr_src_w, ev_w, qn_p, kv_a, agg_p,
                offs_r, csr_src_r, ev_r, qn_a, kv_p, agg_a, NB);

        if (layer == 0) {
            update_kernel<<<gN2, TPB, 0, stream>>>(agg_a, lin_a, h_a, h_a,
                                                   agg_p, lin_p, h_p, h_p, NB);
        } else {
            update_kernel<<<gN2, TPB, 0, stream>>>(agg_a, lin_a, h_a, out_ha,
                                                   agg_p, lin_p, h_p, out_hp, NB);
        }
    }
}